// Round 2
// baseline (666.903 us; speedup 1.0000x reference)
//
#include <hip/hip_runtime.h>
#include <hip/hip_bf16.h>
#include <stdint.h>

// ---------------------------------------------------------------------------
// JointAttention (MMDiT-style) on MI355X / gfx950
// Pipeline: cast->bf16, QKV GEMM (A@B^T, m97-structure), pack(+rope,+scale),
// flash attention (16x16x32 MFMA, swizzled LDS), out-proj GEMM -> fp32 out.
// R1 fix: gemm_bt staged only 64 of 128 tile rows (1 gload_lds16/thread =
// 4096B vs 8192B tile) -> rows 64..127 of As/Bs were uninitialized LDS.
// Now stages 2x 64-row chunks per matrix per K-step.
// ---------------------------------------------------------------------------

typedef __attribute__((ext_vector_type(8))) short bf16x8;   // 8 bf16 (4 VGPRs)
typedef __attribute__((ext_vector_type(4))) float f32x4;    // MFMA C/D frag

#define NUM_HEADS 12
#define HEAD_DIM  128
#define HIDDEN    1536
#define LTXT      512
#define NIMG      4096
#define STOT      4608      // 512 + 4096 joint sequence
#define QKV3      4608      // 3*12*128 qkv width
#define SCALE_Q   0.08838834764831845f  // 128^-0.5

// bf16 <-> f32 helpers (bit-level, RNE)
__device__ __forceinline__ float b2f(short s) {
    union { uint32_t u; float f; } c; c.u = ((uint32_t)(uint16_t)s) << 16; return c.f;
}
__device__ __forceinline__ short f2b(float f) {
    union { float f; uint32_t u; } c; c.f = f;
    uint32_t u = c.u + 0x7FFFu + ((c.u >> 16) & 1u);
    return (short)(u >> 16);
}

// async global->LDS, 16B per lane. LDS dest must be the WAVE-UNIFORM base;
// HW writes base + lane*16. Global src is per-lane.
typedef const void __attribute__((address_space(1)))* gas_p;
typedef void __attribute__((address_space(3)))* las_p;
__device__ __forceinline__ void gload_lds16(const void* g, void* l) {
    __builtin_amdgcn_global_load_lds((gas_p)g, (las_p)l, 16, 0, 0);
}

// ---------------------------------------------------------------------------
// cast fp32 -> bf16, 8 elems/thread
// ---------------------------------------------------------------------------
__global__ __launch_bounds__(256) void cast_f32_bf16(
    const float* __restrict__ in, short* __restrict__ out, int n8)
{
    int i = blockIdx.x * 256 + threadIdx.x;
    if (i >= n8) return;
    const float4* p = (const float4*)in + (size_t)i * 2;
    float4 a = p[0], b = p[1];
    bf16x8 o;
    o[0] = f2b(a.x); o[1] = f2b(a.y); o[2] = f2b(a.z); o[3] = f2b(a.w);
    o[4] = f2b(b.x); o[5] = f2b(b.y); o[6] = f2b(b.z); o[7] = f2b(b.w);
    *((bf16x8*)out + i) = o;
}

// ---------------------------------------------------------------------------
// GEMM: C(MxN) = A(MxK) @ B(NxK)^T, bf16 in, OT out (float or bf16-as-short).
// 128x128 tile, BK=32, 4 waves (2x2), 16x16x32 MFMA, global_load_lds staging.
// M,N multiples of 128; K multiple of 32.
// Staging: chunk i (i=0,1) covers tile rows i*64 + (t>>2); slot e = i*256+t
// lands at LDS byte offset e*16 (linear, as global_load_lds requires).
// ---------------------------------------------------------------------------
template <typename OT>
__global__ __launch_bounds__(256) void gemm_bt(
    const short* __restrict__ A, const short* __restrict__ B, OT* __restrict__ C,
    int M, int N, int K)
{
    __shared__ __align__(16) short As[128 * 32];
    __shared__ __align__(16) short Bs[128 * 32];
    const int t    = threadIdx.x;
    const int lane = t & 63, wid = t >> 6;
    const int wr = wid >> 1, wc = wid & 1;       // 2x2 waves -> 64x64 each
    const int l15 = lane & 15, lk = lane >> 4;
    const int bm = blockIdx.y, bn = blockIdx.x;

    const int srow = t >> 2, skg = t & 3;        // stage: row (0..63), k-group
    const short* Ag = A + (size_t)(bm * 128 + srow) * K + skg * 8;
    const short* Bg = B + (size_t)(bn * 128 + srow) * K + skg * 8;
    const size_t rowblk = (size_t)64 * K;        // +64 rows
    short* As0 = &As[wid * 512];
    short* As1 = &As[2048 + wid * 512];
    short* Bs0 = &Bs[wid * 512];
    short* Bs1 = &Bs[2048 + wid * 512];

    f32x4 acc[4][4];
    const f32x4 z = {0.f, 0.f, 0.f, 0.f};
#pragma unroll
    for (int i = 0; i < 4; ++i)
#pragma unroll
        for (int j = 0; j < 4; ++j) acc[i][j] = z;

    for (int k0 = 0; k0 < K; k0 += 32) {
        gload_lds16(Ag + k0, As0);
        gload_lds16(Ag + rowblk + k0, As1);
        gload_lds16(Bg + k0, Bs0);
        gload_lds16(Bg + rowblk + k0, Bs1);
        asm volatile("s_waitcnt vmcnt(0)" ::: "memory");
        __syncthreads();
        bf16x8 af[4], bfr[4];
#pragma unroll
        for (int i = 0; i < 4; ++i)
            af[i] = *(const bf16x8*)&As[(wr * 64 + i * 16 + l15) * 32 + lk * 8];
#pragma unroll
        for (int j = 0; j < 4; ++j)
            bfr[j] = *(const bf16x8*)&Bs[(wc * 64 + j * 16 + l15) * 32 + lk * 8];
#pragma unroll
        for (int i = 0; i < 4; ++i)
#pragma unroll
            for (int j = 0; j < 4; ++j)
                acc[i][j] = __builtin_amdgcn_mfma_f32_16x16x32_bf16(
                    af[i], bfr[j], acc[i][j], 0, 0, 0);
        __syncthreads();
    }

    // C/D layout: col = lane&15, row = (lane>>4)*4 + reg  [m89-verified]
#pragma unroll
    for (int i = 0; i < 4; ++i) {
#pragma unroll
        for (int j = 0; j < 4; ++j) {
            const int row0 = bm * 128 + wr * 64 + i * 16 + lk * 4;
            const int col  = bn * 128 + wc * 64 + j * 16 + l15;
#pragma unroll
            for (int r = 0; r < 4; ++r) {
                float v = acc[i][j][r];
                if constexpr (sizeof(OT) == 2)
                    C[(size_t)(row0 + r) * N + col] = (OT)f2b(v);
                else
                    C[(size_t)(row0 + r) * N + col] = v;
            }
        }
    }
}

// ---------------------------------------------------------------------------
// pack: Y(txt 512 rows, img 4096 rows) x 4608 cols (q|k|v per head) ->
//   Qb[h][s][d] (rope-applied for img, *SCALE), Kb[h][s][d] (rope for img),
//   VTb[h][d][s] (transposed V via LDS).
// grid (72 s-tiles of 64, 12 heads), 256 thr.
// ---------------------------------------------------------------------------
__global__ __launch_bounds__(256) void pack_qkv(
    const short* __restrict__ Yt, const short* __restrict__ Yi,
    const float* __restrict__ rope,
    short* __restrict__ Qb, short* __restrict__ Kb, short* __restrict__ VTb)
{
    const int st = blockIdx.x, h = blockIdx.y, t = threadIdx.x;
    const int s0 = st * 64;
    __shared__ __align__(16) short Vt[128][72];  // [d][s_local], +8 pad

#pragma unroll
    for (int i = 0; i < 4; ++i) {
        int e  = t + i * 256;          // 0..1023
        int sl = e >> 4, dg = e & 15;  // local row, 8-elem d-group
        int s  = s0 + sl;
        const short* src = (s < LTXT) ? (Yt + (size_t)s * QKV3)
                                      : (Yi + (size_t)(s - LTXT) * QKV3);
        bf16x8 q8 = *(const bf16x8*)(src + h * 128 + dg * 8);
        bf16x8 k8 = *(const bf16x8*)(src + (12 + h) * 128 + dg * 8);
        bf16x8 v8 = *(const bf16x8*)(src + (24 + h) * 128 + dg * 8);
        float qf[8], kf[8];
#pragma unroll
        for (int j = 0; j < 8; ++j) { qf[j] = b2f(q8[j]); kf[j] = b2f(k8[j]); }
        if (s >= LTXT) {
            const float* rp = rope + (size_t)(s - LTXT) * 128 + dg * 8;
            float4 r0 = *(const float4*)rp;
            float4 r1 = *(const float4*)(rp + 4);
            float rr[8] = {r0.x, r0.y, r0.z, r0.w, r1.x, r1.y, r1.z, r1.w};
#pragma unroll
            for (int j = 0; j < 4; ++j) {   // (c,s) per pair: y0=x0*c-x1*s, y1=x1*c+x0*s
                float c = rr[2 * j], sn = rr[2 * j + 1];
                float q0 = qf[2 * j], q1 = qf[2 * j + 1];
                qf[2 * j] = q0 * c - q1 * sn; qf[2 * j + 1] = q1 * c + q0 * sn;
                float k0 = kf[2 * j], k1 = kf[2 * j + 1];
                kf[2 * j] = k0 * c - k1 * sn; kf[2 * j + 1] = k1 * c + k0 * sn;
            }
        }
        bf16x8 qo, ko;
#pragma unroll
        for (int j = 0; j < 8; ++j) { qo[j] = f2b(qf[j] * SCALE_Q); ko[j] = f2b(kf[j]); }
        *(bf16x8*)(Qb + ((size_t)h * STOT + s) * 128 + dg * 8) = qo;
        *(bf16x8*)(Kb + ((size_t)h * STOT + s) * 128 + dg * 8) = ko;
#pragma unroll
        for (int j = 0; j < 8; ++j) Vt[dg * 8 + j][sl] = v8[j];
    }
    __syncthreads();
#pragma unroll
    for (int i = 0; i < 4; ++i) {
        int c = t + i * 256;           // 16B chunk id, 1024 total
        int d = c >> 3, sg = c & 7;
        bf16x8 val = *(const bf16x8*)&Vt[d][sg * 8];
        *(bf16x8*)(VTb + ((size_t)h * 128 + d) * STOT + s0 + sg * 8) = val;
    }
}

// ---------------------------------------------------------------------------
// flash attention: grid (72 q-tiles of 64, 12 heads), 4 waves x 16 q-rows.
// K/V^T staged in XOR-swizzled LDS (G4: [*][128]-row-major is 16/32-way
// conflict; swizzle both sides via pre-swizzled global src, rule #21).
// Online softmax in fp32; P transposed through padded per-wave LDS.
// ---------------------------------------------------------------------------
__global__ __launch_bounds__(256) void attn_fwd(
    const short* __restrict__ Q, const short* __restrict__ Kb,
    const short* __restrict__ VT, short* __restrict__ O)
{
    const int qb = blockIdx.x, h = blockIdx.y, t = threadIdx.x;
    const int lane = t & 63, wid = t >> 6;
    const int l15 = lane & 15, lk = lane >> 4;

    __shared__ __align__(16) short Ks[64 * 128];   // swizzled [key][d]
    __shared__ __align__(16) short Vs[128 * 64];   // swizzled [d][key]
    __shared__ __align__(16) short Ps[4][16 * 72]; // per-wave P, padded rows

    // Q fragments: row = l15, k = dk*32 + lk*8 + j (A-frag layout)
    const short* Qrow = Q + ((size_t)h * STOT + qb * 64 + wid * 16 + l15) * 128;
    bf16x8 qf[4];
#pragma unroll
    for (int dk = 0; dk < 4; ++dk)
        qf[dk] = *(const bf16x8*)(Qrow + dk * 32 + lk * 8);

    f32x4 o[8];
    const f32x4 z = {0.f, 0.f, 0.f, 0.f};
#pragma unroll
    for (int nt = 0; nt < 8; ++nt) o[nt] = z;
    float m[4] = {-1e30f, -1e30f, -1e30f, -1e30f};
    float den[4] = {0.f, 0.f, 0.f, 0.f};

    const short* Kh = Kb + (size_t)h * STOT * 128;
    const short* Vh = VT + (size_t)h * 128 * STOT;

    for (int kb = 0; kb < STOT / 64; ++kb) {
        const int kk0 = kb * 64;
        // stage K tile [64][128]: slot p -> row=p>>4, phys kgrp=p&15,
        // logical kgrp = phys ^ (row&7)  (inverse-swizzled source)
#pragma unroll
        for (int i = 0; i < 4; ++i) {
            int p = t + i * 256;
            int row = p >> 4, kp = p & 15;
            gload_lds16(Kh + (size_t)(kk0 + row) * 128 + ((kp ^ (row & 7)) * 8),
                        &Ks[(i * 256 + wid * 64) * 8]);
        }
        // stage V^T tile [128][64]: row=d=p>>3, phys kgrp=p&7
#pragma unroll
        for (int i = 0; i < 4; ++i) {
            int p = t + i * 256;
            int row = p >> 3, kp = p & 7;
            gload_lds16(Vh + (size_t)row * STOT + kk0 + ((kp ^ (row & 7)) * 8),
                        &Vs[(i * 256 + wid * 64) * 8]);
        }
        asm volatile("s_waitcnt vmcnt(0)" ::: "memory");
        __syncthreads();

        // QK^T: 4 key-tiles of 16, k-dim = 128 = 4 chunks of 32
        f32x4 sc[4];
#pragma unroll
        for (int n = 0; n < 4; ++n) {
            sc[n] = z;
#pragma unroll
            for (int dk = 0; dk < 4; ++dk) {
                int key = n * 16 + l15;
                int kgrp = dk * 4 + lk;
                bf16x8 kfrag = *(const bf16x8*)((const char*)Ks + key * 256 +
                                                (((kgrp ^ (key & 7))) << 4));
                sc[n] = __builtin_amdgcn_mfma_f32_16x16x32_bf16(qf[dk], kfrag, sc[n], 0, 0, 0);
            }
        }

        // online softmax (scores already scaled via Q)
        float al[4], rs[4];
#pragma unroll
        for (int r = 0; r < 4; ++r) {
            float v = fmaxf(fmaxf(sc[0][r], sc[1][r]), fmaxf(sc[2][r], sc[3][r]));
#pragma unroll
            for (int off = 1; off < 16; off <<= 1) v = fmaxf(v, __shfl_xor(v, off));
            float mn = fmaxf(m[r], v);
            al[r] = __expf(m[r] - mn);
            m[r] = mn;
            rs[r] = 0.f;
        }
#pragma unroll
        for (int n = 0; n < 4; ++n) {
#pragma unroll
            for (int r = 0; r < 4; ++r) {
                float pv = __expf(sc[n][r] - m[r]);
                rs[r] += pv;
                Ps[wid][(lk * 4 + r) * 72 + n * 16 + l15] = f2b(pv);
            }
        }
#pragma unroll
        for (int r = 0; r < 4; ++r) {
            float v = rs[r];
#pragma unroll
            for (int off = 1; off < 16; off <<= 1) v += __shfl_xor(v, off);
            den[r] = den[r] * al[r] + v;
        }
#pragma unroll
        for (int nt = 0; nt < 8; ++nt)
#pragma unroll
            for (int r = 0; r < 4; ++r) o[nt][r] *= al[r];

        // PV: P (16x64) @ V (64x128); A-frag from Ps, B-frag from swizzled Vs
#pragma unroll
        for (int kk = 0; kk < 2; ++kk) {
            bf16x8 pf = *(const bf16x8*)&Ps[wid][l15 * 72 + kk * 32 + lk * 8];
#pragma unroll
            for (int nt = 0; nt < 8; ++nt) {
                int d = nt * 16 + l15;
                int kgrp = kk * 4 + lk;
                bf16x8 vfrag = *(const bf16x8*)((const char*)Vs + d * 128 +
                                                ((kgrp ^ (d & 7)) << 4));
                o[nt] = __builtin_amdgcn_mfma_f32_16x16x32_bf16(pf, vfrag, o[nt], 0, 0, 0);
            }
        }
        __syncthreads();
    }

    // epilogue: normalize, write O[s][h*128+d] bf16
    const int qrow0 = qb * 64 + wid * 16 + lk * 4;
#pragma unroll
    for (int nt = 0; nt < 8; ++nt) {
#pragma unroll
        for (int r = 0; r < 4; ++r) {
            float v = o[nt][r] / den[r];
            O[(size_t)(qrow0 + r) * HIDDEN + h * 128 + nt * 16 + l15] = f2b(v);
        }
    }
}

// ---------------------------------------------------------------------------
extern "C" void kernel_launch(void* const* d_in, const int* in_sizes, int n_in,
                              void* d_out, int out_size, void* d_ws, size_t ws_size,
                              hipStream_t stream)
{
    (void)in_sizes; (void)n_in; (void)out_size; (void)ws_size;
    const float* txt  = (const float*)d_in[0];
    const float* img  = (const float*)d_in[1];
    const float* rope = (const float*)d_in[2];
    const float* Wtq  = (const float*)d_in[3];
    const float* Wiq  = (const float*)d_in[4];
    const float* Wto  = (const float*)d_in[5];
    const float* Wio  = (const float*)d_in[6];
    float* out = (float*)d_out;

    short* w = (short*)d_ws;
    size_t off = 0;
    auto alloc = [&](size_t elems) { short* p = w + off; off += elems; return p; };
    short* txtb = alloc((size_t)LTXT * HIDDEN);        // dead after qkv-gemm
    short* imgb = alloc((size_t)NIMG * HIDDEN);
    short* Wtqb = alloc((size_t)QKV3 * HIDDEN);
    short* Wiqb = alloc((size_t)QKV3 * HIDDEN);
    short* Wtob = alloc((size_t)HIDDEN * HIDDEN);
    short* Wiob = alloc((size_t)HIDDEN * HIDDEN);
    short* Yt   = alloc((size_t)LTXT * QKV3);
    short* Yi   = alloc((size_t)NIMG * QKV3);
    short* Qb   = alloc((size_t)NUM_HEADS * STOT * HEAD_DIM);
    short* Kb   = alloc((size_t)NUM_HEADS * STOT * HEAD_DIM);
    short* VTb  = alloc((size_t)NUM_HEADS * STOT * HEAD_DIM);
    short* Ob   = txtb;  // alias: txtb+imgb = 4608*1536 exactly; both dead
                         // after the two QKV GEMMs (attn writes O there)

    auto cast = [&](const float* in, short* o, size_t n) {
        int n8 = (int)(n / 8);
        cast_f32_bf16<<<(n8 + 255) / 256, 256, 0, stream>>>(in, o, n8);
    };
    cast(txt, txtb, (size_t)LTXT * HIDDEN);
    cast(img, imgb, (size_t)NIMG * HIDDEN);
    cast(Wtq, Wtqb, (size_t)QKV3 * HIDDEN);
    cast(Wiq, Wiqb, (size_t)QKV3 * HIDDEN);
    cast(Wto, Wtob, (size_t)HIDDEN * HIDDEN);
    cast(Wio, Wiob, (size_t)HIDDEN * HIDDEN);

    // QKV projections: Y = X @ Wqkv^T  (bf16 out)
    gemm_bt<short><<<dim3(QKV3 / 128, LTXT / 128), 256, 0, stream>>>(
        txtb, Wtqb, Yt, LTXT, QKV3, HIDDEN);
    gemm_bt<short><<<dim3(QKV3 / 128, NIMG / 128), 256, 0, stream>>>(
        imgb, Wiqb, Yi, NIMG, QKV3, HIDDEN);

    // pack + rope + scale -> Q,K,[V^T]
    pack_qkv<<<dim3(STOT / 64, NUM_HEADS), 256, 0, stream>>>(
        Yt, Yi, rope, Qb, Kb, VTb);

    // joint attention
    attn_fwd<<<dim3(STOT / 64, NUM_HEADS), 256, 0, stream>>>(Qb, Kb, VTb, Ob);

    // out projections (fp32 out), txt rows [0,512), img rows [512,4608)
    gemm_bt<float><<<dim3(HIDDEN / 128, LTXT / 128), 256, 0, stream>>>(
        Ob, Wtob, out, LTXT, HIDDEN, HIDDEN);
    gemm_bt<float><<<dim3(HIDDEN / 128, NIMG / 128), 256, 0, stream>>>(
        Ob + (size_t)LTXT * HIDDEN, Wiob, out + (size_t)LTXT * HIDDEN,
        NIMG, HIDDEN, HIDDEN);
}

// Round 3
// 518.560 us; speedup vs baseline: 1.2861x; 1.2861x over previous
//
#include <hip/hip_runtime.h>
#include <hip/hip_bf16.h>
#include <stdint.h>

// ---------------------------------------------------------------------------
// JointAttention (MMDiT-style) on MI355X / gfx950
// R3: attn_fwd 2-phase double-buffered pipeline (counted vmcnt + raw
// s_barrier; __syncthreads would drain vmcnt->0 and kill the pipeline),
// 2-phase GEMM, fused txt+img GEMM launches, fused cast kernel.
// ---------------------------------------------------------------------------

typedef __attribute__((ext_vector_type(8))) short bf16x8;   // 8 bf16 (4 VGPRs)
typedef __attribute__((ext_vector_type(4))) float f32x4;    // MFMA C/D frag

#define NUM_HEADS 12
#define HEAD_DIM  128
#define HIDDEN    1536
#define LTXT      512
#define NIMG      4096
#define STOT      4608      // 512 + 4096 joint sequence
#define QKV3      4608      // 3*12*128 qkv width
#define SCALE_Q   0.08838834764831845f  // 128^-0.5

__device__ __forceinline__ float b2f(short s) {
    union { uint32_t u; float f; } c; c.u = ((uint32_t)(uint16_t)s) << 16; return c.f;
}
__device__ __forceinline__ short f2b(float f) {
    union { float f; uint32_t u; } c; c.f = f;
    uint32_t u = c.u + 0x7FFFu + ((c.u >> 16) & 1u);
    return (short)(u >> 16);
}

typedef const void __attribute__((address_space(1)))* gas_p;
typedef void __attribute__((address_space(3)))* las_p;
__device__ __forceinline__ void gload_lds16(const void* g, void* l) {
    __builtin_amdgcn_global_load_lds((gas_p)g, (las_p)l, 16, 0, 0);
}

// ---------------------------------------------------------------------------
// fused cast fp32 -> bf16 over 6 contiguous-dst segments, 8 elems/thread.
// Segment boundaries are all multiples of 256*8 -> branch is block-uniform.
// ---------------------------------------------------------------------------
__global__ __launch_bounds__(256) void cast6(
    const float* __restrict__ s0, const float* __restrict__ s1,
    const float* __restrict__ s2, const float* __restrict__ s3,
    const float* __restrict__ s4, const float* __restrict__ s5,
    short* __restrict__ dst)
{
    size_t i = (size_t)blockIdx.x * 256 + threadIdx.x;  // units of 8 elems
    const size_t e0 = 98304, e1 = 884736, e2 = 1769472,
                 e3 = 2654208, e4 = 2949120;
    const float* src; size_t base;
    if (i < e2) {
        if (i < e0)      { src = s0; base = 0;  }
        else if (i < e1) { src = s1; base = e0; }
        else             { src = s2; base = e1; }
    } else {
        if (i < e3)      { src = s3; base = e2; }
        else if (i < e4) { src = s4; base = e3; }
        else             { src = s5; base = e4; }
    }
    const float4* p = (const float4*)src + (i - base) * 2;
    float4 a = p[0], b = p[1];
    bf16x8 o;
    o[0] = f2b(a.x); o[1] = f2b(a.y); o[2] = f2b(a.z); o[3] = f2b(a.w);
    o[4] = f2b(b.x); o[5] = f2b(b.y); o[6] = f2b(b.z); o[7] = f2b(b.w);
    *((bf16x8*)dst + i) = o;
}

// ---------------------------------------------------------------------------
// GEMM: C(MxN) = A(MxK) @ Bsel(NxK)^T, Bsel = (bm*128<rowsplit) ? B0 : B1.
// 128x128 tile, BK=32, 2-phase double-buffered staging with counted vmcnt.
// ---------------------------------------------------------------------------
template <typename OT>
__global__ __launch_bounds__(256) void gemm_bt2(
    const short* __restrict__ A, const short* __restrict__ B0,
    const short* __restrict__ B1, OT* __restrict__ C,
    int M, int N, int K, int rowsplit)
{
    __shared__ __align__(16) short As[2][128 * 32];
    __shared__ __align__(16) short Bs[2][128 * 32];
    const int t    = threadIdx.x;
    const int lane = t & 63, wid = t >> 6;
    const int wr = wid >> 1, wc = wid & 1;
    const int l15 = lane & 15, lk = lane >> 4;
    const int bm = blockIdx.y, bn = blockIdx.x;

    const short* B = (bm * 128 < rowsplit) ? B0 : B1;
    const int srow = t >> 2, skg = t & 3;
    const short* Ag = A + (size_t)(bm * 128 + srow) * K + skg * 8;
    const short* Bg = B + (size_t)(bn * 128 + srow) * K + skg * 8;
    const size_t rowblk = (size_t)64 * K;

    f32x4 acc[4][4];
    const f32x4 z = {0.f, 0.f, 0.f, 0.f};
#pragma unroll
    for (int i = 0; i < 4; ++i)
#pragma unroll
        for (int j = 0; j < 4; ++j) acc[i][j] = z;

    auto STAGE = [&](int b, int kt) {
        const int k0 = kt * 32;
        gload_lds16(Ag + k0,          &As[b][wid * 512]);
        gload_lds16(Ag + rowblk + k0, &As[b][2048 + wid * 512]);
        gload_lds16(Bg + k0,          &Bs[b][wid * 512]);
        gload_lds16(Bg + rowblk + k0, &Bs[b][2048 + wid * 512]);
    };

    const int NT = K / 32;
    STAGE(0, 0);
    for (int kt = 0; kt < NT; ++kt) {
        const int cur = kt & 1;
        if (kt + 1 < NT) {
            STAGE(cur ^ 1, kt + 1);
            asm volatile("s_waitcnt vmcnt(4)" ::: "memory");
        } else {
            asm volatile("s_waitcnt vmcnt(0)" ::: "memory");
        }
        __builtin_amdgcn_s_barrier();

        bf16x8 af[4], bfr[4];
#pragma unroll
        for (int i = 0; i < 4; ++i)
            af[i] = *(const bf16x8*)&As[cur][(wr * 64 + i * 16 + l15) * 32 + lk * 8];
#pragma unroll
        for (int j = 0; j < 4; ++j)
            bfr[j] = *(const bf16x8*)&Bs[cur][(wc * 64 + j * 16 + l15) * 32 + lk * 8];
        __builtin_amdgcn_s_setprio(1);
#pragma unroll
        for (int i = 0; i < 4; ++i)
#pragma unroll
            for (int j = 0; j < 4; ++j)
                acc[i][j] = __builtin_amdgcn_mfma_f32_16x16x32_bf16(
                    af[i], bfr[j], acc[i][j], 0, 0, 0);
        __builtin_amdgcn_s_setprio(0);

        asm volatile("s_waitcnt lgkmcnt(0)" ::: "memory");
        __builtin_amdgcn_sched_barrier(0);
        __builtin_amdgcn_s_barrier();
    }

    // C/D layout: col = lane&15, row = (lane>>4)*4 + reg
#pragma unroll
    for (int i = 0; i < 4; ++i) {
#pragma unroll
        for (int j = 0; j < 4; ++j) {
            const int row0 = bm * 128 + wr * 64 + i * 16 + lk * 4;
            const int col  = bn * 128 + wc * 64 + j * 16 + l15;
#pragma unroll
            for (int r = 0; r < 4; ++r) {
                float v = acc[i][j][r];
                if constexpr (sizeof(OT) == 2)
                    C[(size_t)(row0 + r) * N + col] = (OT)f2b(v);
                else
                    C[(size_t)(row0 + r) * N + col] = v;
            }
        }
    }
}

// ---------------------------------------------------------------------------
// pack: Y[4608][4608] (txt rows 0..511, img rows 512..) ->
//   Qb[h][s][d] (*SCALE, rope for img), Kb[h][s][d] (rope for img),
//   VTb[h][d][s] (transposed via LDS).
// ---------------------------------------------------------------------------
__global__ __launch_bounds__(256) void pack_qkv(
    const short* __restrict__ Y, const float* __restrict__ rope,
    short* __restrict__ Qb, short* __restrict__ Kb, short* __restrict__ VTb)
{
    const int st = blockIdx.x, h = blockIdx.y, t = threadIdx.x;
    const int s0 = st * 64;
    __shared__ __align__(16) short Vt[128][72];

#pragma unroll
    for (int i = 0; i < 4; ++i) {
        int e  = t + i * 256;
        int sl = e >> 4, dg = e & 15;
        int s  = s0 + sl;
        const short* src = Y + (size_t)s * QKV3;
        bf16x8 q8 = *(const bf16x8*)(src + h * 128 + dg * 8);
        bf16x8 k8 = *(const bf16x8*)(src + (12 + h) * 128 + dg * 8);
        bf16x8 v8 = *(const bf16x8*)(src + (24 + h) * 128 + dg * 8);
        float qf[8], kf[8];
#pragma unroll
        for (int j = 0; j < 8; ++j) { qf[j] = b2f(q8[j]); kf[j] = b2f(k8[j]); }
        if (s >= LTXT) {
            const float* rp = rope + (size_t)(s - LTXT) * 128 + dg * 8;
            float4 r0 = *(const float4*)rp;
            float4 r1 = *(const float4*)(rp + 4);
            float rr[8] = {r0.x, r0.y, r0.z, r0.w, r1.x, r1.y, r1.z, r1.w};
#pragma unroll
            for (int j = 0; j < 4; ++j) {
                float c = rr[2 * j], sn = rr[2 * j + 1];
                float q0 = qf[2 * j], q1 = qf[2 * j + 1];
                qf[2 * j] = q0 * c - q1 * sn; qf[2 * j + 1] = q1 * c + q0 * sn;
                float k0 = kf[2 * j], k1 = kf[2 * j + 1];
                kf[2 * j] = k0 * c - k1 * sn; kf[2 * j + 1] = k1 * c + k0 * sn;
            }
        }
        bf16x8 qo, ko;
#pragma unroll
        for (int j = 0; j < 8; ++j) { qo[j] = f2b(qf[j] * SCALE_Q); ko[j] = f2b(kf[j]); }
        *(bf16x8*)(Qb + ((size_t)h * STOT + s) * 128 + dg * 8) = qo;
        *(bf16x8*)(Kb + ((size_t)h * STOT + s) * 128 + dg * 8) = ko;
#pragma unroll
        for (int j = 0; j < 8; ++j) Vt[dg * 8 + j][sl] = v8[j];
    }
    __syncthreads();
#pragma unroll
    for (int i = 0; i < 4; ++i) {
        int c = t + i * 256;
        int d = c >> 3, sg = c & 7;
        bf16x8 val = *(const bf16x8*)&Vt[d][sg * 8];
        *(bf16x8*)(VTb + ((size_t)h * 128 + d) * STOT + s0 + sg * 8) = val;
    }
}

// ---------------------------------------------------------------------------
// flash attention, 2-phase pipelined: stage(next tile) issued before
// compute(cur); counted vmcnt(8) keeps next tile's 8 loads in flight across
// raw s_barriers. K/V^T in XOR-swizzled double-buffered LDS.
// ---------------------------------------------------------------------------
__global__ __launch_bounds__(256) void attn_fwd(
    const short* __restrict__ Q, const short* __restrict__ Kb,
    const short* __restrict__ VT, short* __restrict__ O)
{
    const int qb = blockIdx.x, h = blockIdx.y, t = threadIdx.x;
    const int lane = t & 63, wid = t >> 6;
    const int l15 = lane & 15, lk = lane >> 4;

    __shared__ __align__(16) short Ks[2][64 * 128];
    __shared__ __align__(16) short Vs[2][64 * 128];
    __shared__ __align__(16) short Ps[4][16 * 72];

    const short* Qrow = Q + ((size_t)h * STOT + qb * 64 + wid * 16 + l15) * 128;
    bf16x8 qf[4];
#pragma unroll
    for (int dk = 0; dk < 4; ++dk)
        qf[dk] = *(const bf16x8*)(Qrow + dk * 32 + lk * 8);

    f32x4 o[8];
    const f32x4 z = {0.f, 0.f, 0.f, 0.f};
#pragma unroll
    for (int nt = 0; nt < 8; ++nt) o[nt] = z;
    float m[4] = {-1e30f, -1e30f, -1e30f, -1e30f};
    float den[4] = {0.f, 0.f, 0.f, 0.f};

    const short* Kh = Kb + (size_t)h * STOT * 128;
    const short* Vh = VT + (size_t)h * 128 * STOT;

    // hoisted staging sources (chunk i: slot p = t + i*256)
    const short* Ksrc[4];
    const short* Vsrc[4];
    short* Kdst[2][4];
    short* Vdst[2][4];
#pragma unroll
    for (int i = 0; i < 4; ++i) {
        int p = t + i * 256;
        int krow = p >> 4, kxor = (p & 15) ^ (krow & 7);
        Ksrc[i] = Kh + (size_t)krow * 128 + kxor * 8;
        int vrow = p >> 3, vxor = (p & 7) ^ (vrow & 7);
        Vsrc[i] = Vh + (size_t)vrow * STOT + vxor * 8;
#pragma unroll
        for (int b = 0; b < 2; ++b) {
            Kdst[b][i] = &Ks[b][(i * 256 + wid * 64) * 8];
            Vdst[b][i] = &Vs[b][(i * 256 + wid * 64) * 8];
        }
    }

    auto STAGE = [&](int b, int kb) {
#pragma unroll
        for (int i = 0; i < 4; ++i) {
            gload_lds16(Ksrc[i] + (size_t)kb * 8192, Kdst[b][i]);
            gload_lds16(Vsrc[i] + (size_t)kb * 64,   Vdst[b][i]);
        }
    };

    const int NT = STOT / 64;  // 72
    STAGE(0, 0);
    for (int kb = 0; kb < NT; ++kb) {
        const int cur = kb & 1;
        if (kb + 1 < NT) {
            STAGE(cur ^ 1, kb + 1);
            asm volatile("s_waitcnt vmcnt(8)" ::: "memory");
        } else {
            asm volatile("s_waitcnt vmcnt(0)" ::: "memory");
        }
        __builtin_amdgcn_s_barrier();

        const char* Ksc = (const char*)&Ks[cur][0];
        const char* Vsc = (const char*)&Vs[cur][0];

        // QK^T
        f32x4 sc[4];
        __builtin_amdgcn_s_setprio(1);
#pragma unroll
        for (int n = 0; n < 4; ++n) {
            sc[n] = z;
#pragma unroll
            for (int dk = 0; dk < 4; ++dk) {
                int key = n * 16 + l15;
                int kgrp = dk * 4 + lk;
                bf16x8 kfrag = *(const bf16x8*)(Ksc + key * 256 +
                                                ((kgrp ^ (key & 7)) << 4));
                sc[n] = __builtin_amdgcn_mfma_f32_16x16x32_bf16(qf[dk], kfrag, sc[n], 0, 0, 0);
            }
        }
        __builtin_amdgcn_s_setprio(0);

        // online softmax
        float al[4], rs[4];
#pragma unroll
        for (int r = 0; r < 4; ++r) {
            float v = fmaxf(fmaxf(sc[0][r], sc[1][r]), fmaxf(sc[2][r], sc[3][r]));
#pragma unroll
            for (int off = 1; off < 16; off <<= 1) v = fmaxf(v, __shfl_xor(v, off));
            float mn = fmaxf(m[r], v);
            al[r] = __expf(m[r] - mn);
            m[r] = mn;
            rs[r] = 0.f;
        }
#pragma unroll
        for (int n = 0; n < 4; ++n) {
#pragma unroll
            for (int r = 0; r < 4; ++r) {
                float pv = __expf(sc[n][r] - m[r]);
                rs[r] += pv;
                Ps[wid][(lk * 4 + r) * 72 + n * 16 + l15] = f2b(pv);
            }
        }
#pragma unroll
        for (int r = 0; r < 4; ++r) {
            float v = rs[r];
#pragma unroll
            for (int off = 1; off < 16; off <<= 1) v += __shfl_xor(v, off);
            den[r] = den[r] * al[r] + v;
        }
#pragma unroll
        for (int nt = 0; nt < 8; ++nt)
#pragma unroll
            for (int r = 0; r < 4; ++r) o[nt][r] *= al[r];

        // PV
        __builtin_amdgcn_s_setprio(1);
#pragma unroll
        for (int kk = 0; kk < 2; ++kk) {
            bf16x8 pf = *(const bf16x8*)&Ps[wid][l15 * 72 + kk * 32 + lk * 8];
#pragma unroll
            for (int nt = 0; nt < 8; ++nt) {
                int d = nt * 16 + l15;
                int kgrp = kk * 4 + lk;
                bf16x8 vfrag = *(const bf16x8*)(Vsc + d * 128 +
                                                ((kgrp ^ (d & 7)) << 4));
                o[nt] = __builtin_amdgcn_mfma_f32_16x16x32_bf16(pf, vfrag, o[nt], 0, 0, 0);
            }
        }
        __builtin_amdgcn_s_setprio(0);

        asm volatile("s_waitcnt lgkmcnt(0)" ::: "memory");
        __builtin_amdgcn_sched_barrier(0);
        __builtin_amdgcn_s_barrier();
    }

    const int qrow0 = qb * 64 + wid * 16 + lk * 4;
#pragma unroll
    for (int nt = 0; nt < 8; ++nt) {
#pragma unroll
        for (int r = 0; r < 4; ++r) {
            float v = o[nt][r] / den[r];
            O[(size_t)(qrow0 + r) * HIDDEN + h * 128 + nt * 16 + l15] = f2b(v);
        }
    }
}

// ---------------------------------------------------------------------------
extern "C" void kernel_launch(void* const* d_in, const int* in_sizes, int n_in,
                              void* d_out, int out_size, void* d_ws, size_t ws_size,
                              hipStream_t stream)
{
    (void)in_sizes; (void)n_in; (void)out_size; (void)ws_size;
    const float* txt  = (const float*)d_in[0];
    const float* img  = (const float*)d_in[1];
    const float* rope = (const float*)d_in[2];
    const float* Wtq  = (const float*)d_in[3];
    const float* Wiq  = (const float*)d_in[4];
    const float* Wto  = (const float*)d_in[5];
    const float* Wio  = (const float*)d_in[6];
    float* out = (float*)d_out;

    short* w = (short*)d_ws;
    size_t off = 0;
    auto alloc = [&](size_t elems) { short* p = w + off; off += elems; return p; };
    short* txtb = alloc((size_t)LTXT * HIDDEN);   // txtb..Wiob contiguous = cast6 dst
    short* imgb = alloc((size_t)NIMG * HIDDEN);
    short* Wtqb = alloc((size_t)QKV3 * HIDDEN);
    short* Wiqb = alloc((size_t)QKV3 * HIDDEN);
    short* Wtob = alloc((size_t)HIDDEN * HIDDEN);
    short* Wiob = alloc((size_t)HIDDEN * HIDDEN);
    short* Yt   = alloc((size_t)LTXT * QKV3);     // Yt||Yi = Y[4608][4608]
    short* Yi   = alloc((size_t)NIMG * QKV3);
    short* Qb   = alloc((size_t)NUM_HEADS * STOT * HEAD_DIM);
    short* Kb   = alloc((size_t)NUM_HEADS * STOT * HEAD_DIM);
    short* VTb  = alloc((size_t)NUM_HEADS * STOT * HEAD_DIM);
    (void)imgb; (void)Yi;
    short* Ob   = txtb;  // txtb+imgb = 4608*1536, dead after QKV GEMM

    cast6<<<12672, 256, 0, stream>>>(txt, img, Wtq, Wiq, Wto, Wio, txtb);

    // fused QKV projection: rows 0..511 use Wtq, 512.. use Wiq
    gemm_bt2<short><<<dim3(QKV3 / 128, STOT / 128), 256, 0, stream>>>(
        txtb, Wtqb, Wiqb, Yt, STOT, QKV3, HIDDEN, LTXT);

    pack_qkv<<<dim3(STOT / 64, NUM_HEADS), 256, 0, stream>>>(
        Yt, rope, Qb, Kb, VTb);

    attn_fwd<<<dim3(STOT / 64, NUM_HEADS), 256, 0, stream>>>(Qb, Kb, VTb, Ob);

    // fused out projection: rows 0..511 use Wto, 512.. use Wio
    gemm_bt2<float><<<dim3(HIDDEN / 128, STOT / 128), 256, 0, stream>>>(
        Ob, Wtob, Wiob, out, STOT, HIDDEN, HIDDEN, LTXT);
}

// Round 4
// 414.786 us; speedup vs baseline: 1.6078x; 1.2502x over previous
//
#include <hip/hip_runtime.h>
#include <hip/hip_bf16.h>
#include <stdint.h>

// ---------------------------------------------------------------------------
// JointAttention (MMDiT-style) on MI355X / gfx950
// R4: attn softmax fully in-register via swapped QK^T (S^T = mfma(K,Q):
// lane owns one q-row => row reduce = 15 lane-local ops + 2 shfl_xor),
// exp2-domain softmax (log2e folded into Q scale), defer-max rescale,
// packed b64 P writes, O^T accumulation (q-col = l15 matches lane-local
// m/den). All LDS MFMA-fragment addresses identical to R3 (A/B frags of
// 16x16x32 share the same lane layout) -- only operand order changed.
// ---------------------------------------------------------------------------

typedef __attribute__((ext_vector_type(8))) short bf16x8;   // 8 bf16 (4 VGPRs)
typedef __attribute__((ext_vector_type(4))) float f32x4;    // MFMA C/D frag
typedef __attribute__((ext_vector_type(4))) short s16x4;    // packed 4x bf16

#define NUM_HEADS 12
#define HEAD_DIM  128
#define HIDDEN    1536
#define LTXT      512
#define NIMG      4096
#define STOT      4608      // 512 + 4096 joint sequence
#define QKV3      4608      // 3*12*128 qkv width
// 128^-0.5 * log2(e): scores computed in exp2 domain
#define SCALE_Q2  (0.08838834764831845f * 1.44269504088896340f)
#define DEFER_THR 12.0f     // exp2-domain defer-max threshold (~8.3 nats)

__device__ __forceinline__ float b2f(short s) {
    union { uint32_t u; float f; } c; c.u = ((uint32_t)(uint16_t)s) << 16; return c.f;
}
__device__ __forceinline__ short f2b(float f) {
    union { float f; uint32_t u; } c; c.f = f;
    uint32_t u = c.u + 0x7FFFu + ((c.u >> 16) & 1u);
    return (short)(u >> 16);
}
__device__ __forceinline__ float fexp2(float x) {
#if __has_builtin(__builtin_amdgcn_exp2f)
    return __builtin_amdgcn_exp2f(x);
#else
    return exp2f(x);
#endif
}

typedef const void __attribute__((address_space(1)))* gas_p;
typedef void __attribute__((address_space(3)))* las_p;
__device__ __forceinline__ void gload_lds16(const void* g, void* l) {
    __builtin_amdgcn_global_load_lds((gas_p)g, (las_p)l, 16, 0, 0);
}

// ---------------------------------------------------------------------------
// fused cast fp32 -> bf16 over 6 contiguous-dst segments, 8 elems/thread.
// ---------------------------------------------------------------------------
__global__ __launch_bounds__(256) void cast6(
    const float* __restrict__ s0, const float* __restrict__ s1,
    const float* __restrict__ s2, const float* __restrict__ s3,
    const float* __restrict__ s4, const float* __restrict__ s5,
    short* __restrict__ dst)
{
    size_t i = (size_t)blockIdx.x * 256 + threadIdx.x;  // units of 8 elems
    const size_t e0 = 98304, e1 = 884736, e2 = 1769472,
                 e3 = 2654208, e4 = 2949120;
    const float* src; size_t base;
    if (i < e2) {
        if (i < e0)      { src = s0; base = 0;  }
        else if (i < e1) { src = s1; base = e0; }
        else             { src = s2; base = e1; }
    } else {
        if (i < e3)      { src = s3; base = e2; }
        else if (i < e4) { src = s4; base = e3; }
        else             { src = s5; base = e4; }
    }
    const float4* p = (const float4*)src + (i - base) * 2;
    float4 a = p[0], b = p[1];
    bf16x8 o;
    o[0] = f2b(a.x); o[1] = f2b(a.y); o[2] = f2b(a.z); o[3] = f2b(a.w);
    o[4] = f2b(b.x); o[5] = f2b(b.y); o[6] = f2b(b.z); o[7] = f2b(b.w);
    *((bf16x8*)dst + i) = o;
}

// ---------------------------------------------------------------------------
// GEMM: C(MxN) = A(MxK) @ Bsel(NxK)^T, Bsel = (bm*128<rowsplit) ? B0 : B1.
// 128x128 tile, BK=32, 2-phase double-buffered staging with counted vmcnt.
// ---------------------------------------------------------------------------
template <typename OT>
__global__ __launch_bounds__(256) void gemm_bt2(
    const short* __restrict__ A, const short* __restrict__ B0,
    const short* __restrict__ B1, OT* __restrict__ C,
    int M, int N, int K, int rowsplit)
{
    __shared__ __align__(16) short As[2][128 * 32];
    __shared__ __align__(16) short Bs[2][128 * 32];
    const int t    = threadIdx.x;
    const int lane = t & 63, wid = t >> 6;
    const int wr = wid >> 1, wc = wid & 1;
    const int l15 = lane & 15, lk = lane >> 4;
    const int bm = blockIdx.y, bn = blockIdx.x;

    const short* B = (bm * 128 < rowsplit) ? B0 : B1;
    const int srow = t >> 2, skg = t & 3;
    const short* Ag = A + (size_t)(bm * 128 + srow) * K + skg * 8;
    const short* Bg = B + (size_t)(bn * 128 + srow) * K + skg * 8;
    const size_t rowblk = (size_t)64 * K;

    f32x4 acc[4][4];
    const f32x4 z = {0.f, 0.f, 0.f, 0.f};
#pragma unroll
    for (int i = 0; i < 4; ++i)
#pragma unroll
        for (int j = 0; j < 4; ++j) acc[i][j] = z;

    auto STAGE = [&](int b, int kt) {
        const int k0 = kt * 32;
        gload_lds16(Ag + k0,          &As[b][wid * 512]);
        gload_lds16(Ag + rowblk + k0, &As[b][2048 + wid * 512]);
        gload_lds16(Bg + k0,          &Bs[b][wid * 512]);
        gload_lds16(Bg + rowblk + k0, &Bs[b][2048 + wid * 512]);
    };

    const int NT = K / 32;
    STAGE(0, 0);
    for (int kt = 0; kt < NT; ++kt) {
        const int cur = kt & 1;
        if (kt + 1 < NT) {
            STAGE(cur ^ 1, kt + 1);
            asm volatile("s_waitcnt vmcnt(4)" ::: "memory");
        } else {
            asm volatile("s_waitcnt vmcnt(0)" ::: "memory");
        }
        __builtin_amdgcn_s_barrier();

        bf16x8 af[4], bfr[4];
#pragma unroll
        for (int i = 0; i < 4; ++i)
            af[i] = *(const bf16x8*)&As[cur][(wr * 64 + i * 16 + l15) * 32 + lk * 8];
#pragma unroll
        for (int j = 0; j < 4; ++j)
            bfr[j] = *(const bf16x8*)&Bs[cur][(wc * 64 + j * 16 + l15) * 32 + lk * 8];
        __builtin_amdgcn_s_setprio(1);
#pragma unroll
        for (int i = 0; i < 4; ++i)
#pragma unroll
            for (int j = 0; j < 4; ++j)
                acc[i][j] = __builtin_amdgcn_mfma_f32_16x16x32_bf16(
                    af[i], bfr[j], acc[i][j], 0, 0, 0);
        __builtin_amdgcn_s_setprio(0);

        asm volatile("s_waitcnt lgkmcnt(0)" ::: "memory");
        __builtin_amdgcn_sched_barrier(0);
        __builtin_amdgcn_s_barrier();
    }

    // C/D layout: col = lane&15, row = (lane>>4)*4 + reg
#pragma unroll
    for (int i = 0; i < 4; ++i) {
#pragma unroll
        for (int j = 0; j < 4; ++j) {
            const int row0 = bm * 128 + wr * 64 + i * 16 + lk * 4;
            const int col  = bn * 128 + wc * 64 + j * 16 + l15;
#pragma unroll
            for (int r = 0; r < 4; ++r) {
                float v = acc[i][j][r];
                if constexpr (sizeof(OT) == 2)
                    C[(size_t)(row0 + r) * N + col] = (OT)f2b(v);
                else
                    C[(size_t)(row0 + r) * N + col] = v;
            }
        }
    }
}

// ---------------------------------------------------------------------------
// pack: Y[4608][4608] (txt rows 0..511, img rows 512..) ->
//   Qb[h][s][d] (*SCALE_Q2 incl. log2e, rope for img), Kb[h][s][d] (rope),
//   VTb[h][d][s] (transposed via LDS).
// ---------------------------------------------------------------------------
__global__ __launch_bounds__(256) void pack_qkv(
    const short* __restrict__ Y, const float* __restrict__ rope,
    short* __restrict__ Qb, short* __restrict__ Kb, short* __restrict__ VTb)
{
    const int st = blockIdx.x, h = blockIdx.y, t = threadIdx.x;
    const int s0 = st * 64;
    __shared__ __align__(16) short Vt[128][72];

#pragma unroll
    for (int i = 0; i < 4; ++i) {
        int e  = t + i * 256;
        int sl = e >> 4, dg = e & 15;
        int s  = s0 + sl;
        const short* src = Y + (size_t)s * QKV3;
        bf16x8 q8 = *(const bf16x8*)(src + h * 128 + dg * 8);
        bf16x8 k8 = *(const bf16x8*)(src + (12 + h) * 128 + dg * 8);
        bf16x8 v8 = *(const bf16x8*)(src + (24 + h) * 128 + dg * 8);
        float qf[8], kf[8];
#pragma unroll
        for (int j = 0; j < 8; ++j) { qf[j] = b2f(q8[j]); kf[j] = b2f(k8[j]); }
        if (s >= LTXT) {
            const float* rp = rope + (size_t)(s - LTXT) * 128 + dg * 8;
            float4 r0 = *(const float4*)rp;
            float4 r1 = *(const float4*)(rp + 4);
            float rr[8] = {r0.x, r0.y, r0.z, r0.w, r1.x, r1.y, r1.z, r1.w};
#pragma unroll
            for (int j = 0; j < 4; ++j) {
                float c = rr[2 * j], sn = rr[2 * j + 1];
                float q0 = qf[2 * j], q1 = qf[2 * j + 1];
                qf[2 * j] = q0 * c - q1 * sn; qf[2 * j + 1] = q1 * c + q0 * sn;
                float k0 = kf[2 * j], k1 = kf[2 * j + 1];
                kf[2 * j] = k0 * c - k1 * sn; kf[2 * j + 1] = k1 * c + k0 * sn;
            }
        }
        bf16x8 qo, ko;
#pragma unroll
        for (int j = 0; j < 8; ++j) { qo[j] = f2b(qf[j] * SCALE_Q2); ko[j] = f2b(kf[j]); }
        *(bf16x8*)(Qb + ((size_t)h * STOT + s) * 128 + dg * 8) = qo;
        *(bf16x8*)(Kb + ((size_t)h * STOT + s) * 128 + dg * 8) = ko;
#pragma unroll
        for (int j = 0; j < 8; ++j) Vt[dg * 8 + j][sl] = v8[j];
    }
    __syncthreads();
#pragma unroll
    for (int i = 0; i < 4; ++i) {
        int c = t + i * 256;
        int d = c >> 3, sg = c & 7;
        bf16x8 val = *(const bf16x8*)&Vt[d][sg * 8];
        *(bf16x8*)(VTb + ((size_t)h * 128 + d) * STOT + s0 + sg * 8) = val;
    }
}

// ---------------------------------------------------------------------------
// flash attention, 2-phase pipelined + in-register softmax.
// Lane (l15, lk) of wave wid owns q-row = qb*64 + wid*16 + l15.
// QK^T swapped: sc[n][r] = S^T[key = n*16+lk*4+r][q=l15] (exp2 domain).
// PV as O^T: o[nt] rows d = nt*16+lk*4+r, col q = l15.
// ---------------------------------------------------------------------------
__global__ __launch_bounds__(256) void attn_fwd(
    const short* __restrict__ Q, const short* __restrict__ Kb,
    const short* __restrict__ VT, short* __restrict__ O)
{
    const int qb = blockIdx.x, h = blockIdx.y, t = threadIdx.x;
    const int lane = t & 63, wid = t >> 6;
    const int l15 = lane & 15, lk = lane >> 4;

    __shared__ __align__(16) short Ks[2][64 * 128];
    __shared__ __align__(16) short Vs[2][64 * 128];
    __shared__ __align__(16) short Ps[4][16 * 72];

    // Q B-frag: q = l15, k = dk*32 + lk*8 + j
    const short* Qrow = Q + ((size_t)h * STOT + qb * 64 + wid * 16 + l15) * 128;
    bf16x8 qf[4];
#pragma unroll
    for (int dk = 0; dk < 4; ++dk)
        qf[dk] = *(const bf16x8*)(Qrow + dk * 32 + lk * 8);

    f32x4 o[8];
    const f32x4 z = {0.f, 0.f, 0.f, 0.f};
#pragma unroll
    for (int nt = 0; nt < 8; ++nt) o[nt] = z;
    float m = -1e30f, den = 0.f;   // lane-local: one q-row per lane

    const short* Kh = Kb + (size_t)h * STOT * 128;
    const short* Vh = VT + (size_t)h * 128 * STOT;

    // hoisted staging sources (chunk i: slot p = t + i*256)
    const short* Ksrc[4];
    const short* Vsrc[4];
    short* Kdst[2][4];
    short* Vdst[2][4];
#pragma unroll
    for (int i = 0; i < 4; ++i) {
        int p = t + i * 256;
        int krow = p >> 4, kxor = (p & 15) ^ (krow & 7);
        Ksrc[i] = Kh + (size_t)krow * 128 + kxor * 8;
        int vrow = p >> 3, vxor = (p & 7) ^ (vrow & 7);
        Vsrc[i] = Vh + (size_t)vrow * STOT + vxor * 8;
#pragma unroll
        for (int b = 0; b < 2; ++b) {
            Kdst[b][i] = &Ks[b][(i * 256 + wid * 64) * 8];
            Vdst[b][i] = &Vs[b][(i * 256 + wid * 64) * 8];
        }
    }

    auto STAGE = [&](int b, int kb) {
#pragma unroll
        for (int i = 0; i < 4; ++i) {
            gload_lds16(Ksrc[i] + (size_t)kb * 8192, Kdst[b][i]);
            gload_lds16(Vsrc[i] + (size_t)kb * 64,   Vdst[b][i]);
        }
    };

    const int NT = STOT / 64;  // 72
    STAGE(0, 0);
    for (int kb = 0; kb < NT; ++kb) {
        const int cur = kb & 1;
        if (kb + 1 < NT) {
            STAGE(cur ^ 1, kb + 1);
            asm volatile("s_waitcnt vmcnt(8)" ::: "memory");
        } else {
            asm volatile("s_waitcnt vmcnt(0)" ::: "memory");
        }
        __builtin_amdgcn_s_barrier();

        const char* Ksc = (const char*)&Ks[cur][0];
        const char* Vsc = (const char*)&Vs[cur][0];

        // QK^T (swapped): sc[n] = K-tile(n) x Q  -> S^T fragment
        f32x4 sc[4];
        __builtin_amdgcn_s_setprio(1);
#pragma unroll
        for (int n = 0; n < 4; ++n) {
            sc[n] = z;
#pragma unroll
            for (int dk = 0; dk < 4; ++dk) {
                int key = n * 16 + l15;
                int kgrp = dk * 4 + lk;
                bf16x8 kfrag = *(const bf16x8*)(Ksc + key * 256 +
                                                ((kgrp ^ (key & 7)) << 4));
                sc[n] = __builtin_amdgcn_mfma_f32_16x16x32_bf16(kfrag, qf[dk], sc[n], 0, 0, 0);
            }
        }
        __builtin_amdgcn_s_setprio(0);

        // in-register online softmax (exp2 domain), lane-local q-row
        float v = sc[0][0];
#pragma unroll
        for (int n = 0; n < 4; ++n)
#pragma unroll
            for (int r = 0; r < 4; ++r) v = fmaxf(v, sc[n][r]);
        v = fmaxf(v, __shfl_xor(v, 16));
        v = fmaxf(v, __shfl_xor(v, 32));
        if (__any(v > m + DEFER_THR)) {       // wave-uniform rescale
            float mn = fmaxf(m, v);
            float al = fexp2(m - mn);
            m = mn;
            den *= al;
#pragma unroll
            for (int nt = 0; nt < 8; ++nt) o[nt] *= al;
        }
        float rs = 0.f;
        s16x4 pk[4];
#pragma unroll
        for (int n = 0; n < 4; ++n) {
#pragma unroll
            for (int r = 0; r < 4; ++r) {
                float p = fexp2(sc[n][r] - m);
                rs += p;
                pk[n][r] = f2b(p);
            }
        }
        rs += __shfl_xor(rs, 16);
        rs += __shfl_xor(rs, 32);
        den += rs;
        // P[q=l15][key]: 4 packed b64 writes (cols n*16+lk*4 .. +3)
#pragma unroll
        for (int n = 0; n < 4; ++n)
            *(s16x4*)&Ps[wid][l15 * 72 + n * 16 + lk * 4] = pk[n];
        asm volatile("s_waitcnt lgkmcnt(0)" ::: "memory");
        __builtin_amdgcn_sched_barrier(0);

        // PV as O^T: o[nt] += V^T-frag(nt,kk) x P-frag(kk)
        __builtin_amdgcn_s_setprio(1);
#pragma unroll
        for (int kk = 0; kk < 2; ++kk) {
            bf16x8 pf = *(const bf16x8*)&Ps[wid][l15 * 72 + kk * 32 + lk * 8];
#pragma unroll
            for (int nt = 0; nt < 8; ++nt) {
                int d = nt * 16 + l15;
                int kgrp = kk * 4 + lk;
                bf16x8 vfrag = *(const bf16x8*)(Vsc + d * 128 +
                                                ((kgrp ^ (d & 7)) << 4));
                o[nt] = __builtin_amdgcn_mfma_f32_16x16x32_bf16(vfrag, pf, o[nt], 0, 0, 0);
            }
        }
        __builtin_amdgcn_s_setprio(0);

        asm volatile("s_waitcnt lgkmcnt(0)" ::: "memory");
        __builtin_amdgcn_sched_barrier(0);
        __builtin_amdgcn_s_barrier();
    }

    // epilogue: lane-local normalize; write 4 consecutive d per store
    const int qrow = qb * 64 + wid * 16 + l15;
    float inv = 1.0f / den;
    short* Orow = O + (size_t)qrow * HIDDEN + h * 128;
#pragma unroll
    for (int nt = 0; nt < 8; ++nt) {
        s16x4 w4;
#pragma unroll
        for (int r = 0; r < 4; ++r) w4[r] = f2b(o[nt][r] * inv);
        *(s16x4*)(Orow + nt * 16 + lk * 4) = w4;
    }
}

// ---------------------------------------------------------------------------
extern "C" void kernel_launch(void* const* d_in, const int* in_sizes, int n_in,
                              void* d_out, int out_size, void* d_ws, size_t ws_size,
                              hipStream_t stream)
{
    (void)in_sizes; (void)n_in; (void)out_size; (void)ws_size;
    const float* txt  = (const float*)d_in[0];
    const float* img  = (const float*)d_in[1];
    const float* rope = (const float*)d_in[2];
    const float* Wtq  = (const float*)d_in[3];
    const float* Wiq  = (const float*)d_in[4];
    const float* Wto  = (const float*)d_in[5];
    const float* Wio  = (const float*)d_in[6];
    float* out = (float*)d_out;

    short* w = (short*)d_ws;
    size_t off = 0;
    auto alloc = [&](size_t elems) { short* p = w + off; off += elems; return p; };
    short* txtb = alloc((size_t)LTXT * HIDDEN);   // txtb..Wiob contiguous = cast6 dst
    short* imgb = alloc((size_t)NIMG * HIDDEN);
    short* Wtqb = alloc((size_t)QKV3 * HIDDEN);
    short* Wiqb = alloc((size_t)QKV3 * HIDDEN);
    short* Wtob = alloc((size_t)HIDDEN * HIDDEN);
    short* Wiob = alloc((size_t)HIDDEN * HIDDEN);
    short* Yt   = alloc((size_t)LTXT * QKV3);     // Yt||Yi = Y[4608][4608]
    short* Yi   = alloc((size_t)NIMG * QKV3);
    short* Qb   = alloc((size_t)NUM_HEADS * STOT * HEAD_DIM);
    short* Kb   = alloc((size_t)NUM_HEADS * STOT * HEAD_DIM);
    short* VTb  = alloc((size_t)NUM_HEADS * STOT * HEAD_DIM);
    (void)imgb; (void)Yi;
    short* Ob   = txtb;  // txtb+imgb = 4608*1536, dead after QKV GEMM

    cast6<<<12672, 256, 0, stream>>>(txt, img, Wtq, Wiq, Wto, Wio, txtb);

    // fused QKV projection: rows 0..511 use Wtq, 512.. use Wiq
    gemm_bt2<short><<<dim3(QKV3 / 128, STOT / 128), 256, 0, stream>>>(
        txtb, Wtqb, Wiqb, Yt, STOT, QKV3, HIDDEN, LTXT);

    pack_qkv<<<dim3(STOT / 64, NUM_HEADS), 256, 0, stream>>>(
        Yt, rope, Qb, Kb, VTb);

    attn_fwd<<<dim3(STOT / 64, NUM_HEADS), 256, 0, stream>>>(Qb, Kb, VTb, Ob);

    // fused out projection: rows 0..511 use Wto, 512.. use Wio
    gemm_bt2<float><<<dim3(HIDDEN / 128, STOT / 128), 256, 0, stream>>>(
        Ob, Wtob, Wiob, out, STOT, HIDDEN, HIDDEN, LTXT);
}